// Round 1
// baseline (1156.189 us; speedup 1.0000x reference)
//
#include <hip/hip_runtime.h>
#include <hip/hip_bf16.h>

#define H 1024
#define B 32
#define S 2048

typedef __attribute__((ext_vector_type(8))) short short8;
typedef __attribute__((ext_vector_type(4))) float f32x4;
typedef __attribute__((ext_vector_type(4))) unsigned short ush4;

__device__ __forceinline__ unsigned short f2bf(float f) {
    union { float f; unsigned u; } c; c.f = f;
    unsigned r = c.u + 0x7FFFu + ((c.u >> 16) & 1u);
    return (unsigned short)(r >> 16);
}
__device__ __forceinline__ float bf2f(unsigned short h) {
    union { unsigned u; float f; } c; c.u = ((unsigned)h) << 16;
    return c.f;
}

// ---------------- proj_h = h @ Wh^T + b_attn  (32 x 1024) ----------------
__global__ __launch_bounds__(256) void proj_h_kernel(
    const float* __restrict__ hidden, const float* __restrict__ W,
    const float* __restrict__ b_attn, float* __restrict__ ph)
{
    int b = blockIdx.y;
    int o = blockIdx.x * 256 + threadIdx.x;
    __shared__ float hs[H];
    const float4* hr = (const float4*)(hidden + (size_t)(B + b) * H); // hidden[-1]
    ((float4*)hs)[threadIdx.x] = hr[threadIdx.x];
    __syncthreads();
    const float4* wr = (const float4*)(W + (size_t)o * (2 * H)); // Wh row o
    float acc = b_attn[o];
    #pragma unroll 4
    for (int k = 0; k < H / 4; ++k) {
        float4 w4 = wr[k];
        acc += hs[4*k] * w4.x + hs[4*k+1] * w4.y + hs[4*k+2] * w4.z + hs[4*k+3] * w4.w;
    }
    ph[b * H + o] = acc;
}

// ------- fused scores: scores[b,s] = sum_o v[o]*tanh(enc@We^T + ph) -------
// 3-pass split-bf16 MFMA (hi*hi + hi*lo + lo*hi) for fp32-level accuracy.
// Block: 256 thr = 4 waves (2x2), tile BM=128 rows, loops all 8 N-chunks of 128.
#define BM 128
#define BK 64
__global__ __launch_bounds__(256) void score_gemm(
    const float* __restrict__ enc, const float* __restrict__ W,
    const float* __restrict__ ph, const float* __restrict__ v,
    float* __restrict__ scores)
{
    __shared__ unsigned short Ahi[BM*BK], Alo[BM*BK], Bhi[BM*BK], Blo[BM*BK];
    __shared__ float slds[256];
    const int tid  = threadIdx.x;
    const int mt   = blockIdx.x;            // 0..511
    const int lane = tid & 63;
    const int wid  = tid >> 6;
    const int wr   = wid >> 1, wc = wid & 1;
    const int l15  = lane & 15, lg = lane >> 4;
    const int b    = mt >> 4;               // 16 M-tiles per batch (2048/128)
    const float* encM = enc + (size_t)mt * BM * H;

    slds[tid] = 0.f;
    const int sc4 = (tid & 15) * 4;         // k-offset (4 floats) this thread stages
    const int rbase = tid >> 4;             // row sub-index

    for (int nt = 0; nt < 8; ++nt) {
        f32x4 acc[4][4];
        #pragma unroll
        for (int mi = 0; mi < 4; ++mi)
            #pragma unroll
            for (int ni = 0; ni < 4; ++ni) acc[mi][ni] = (f32x4){0.f,0.f,0.f,0.f};

        const float* Wn = W + (size_t)(nt * 128) * (2 * H) + H;  // We rows for this N-chunk

        for (int kt = 0; kt < H / BK; ++kt) {
            __syncthreads();
            const int k0 = kt * BK;
            #pragma unroll
            for (int i = 0; i < 8; ++i) {
                const int row = i * 16 + rbase;
                const int idx = row * BK + (sc4 ^ ((row & 7) << 3)); // XOR swizzle
                // A tile (encoder rows)
                float4 a4 = *(const float4*)(encM + (size_t)row * H + k0 + sc4);
                ush4 h4, l4;
                { float f = a4.x; unsigned short hh = f2bf(f); h4.x = hh; l4.x = f2bf(f - bf2f(hh)); }
                { float f = a4.y; unsigned short hh = f2bf(f); h4.y = hh; l4.y = f2bf(f - bf2f(hh)); }
                { float f = a4.z; unsigned short hh = f2bf(f); h4.z = hh; l4.z = f2bf(f - bf2f(hh)); }
                { float f = a4.w; unsigned short hh = f2bf(f); h4.w = hh; l4.w = f2bf(f - bf2f(hh)); }
                *(ush4*)&Ahi[idx] = h4;
                *(ush4*)&Alo[idx] = l4;
                // B tile (We rows)
                float4 b4 = *(const float4*)(Wn + (size_t)row * (2 * H) + k0 + sc4);
                { float f = b4.x; unsigned short hh = f2bf(f); h4.x = hh; l4.x = f2bf(f - bf2f(hh)); }
                { float f = b4.y; unsigned short hh = f2bf(f); h4.y = hh; l4.y = f2bf(f - bf2f(hh)); }
                { float f = b4.z; unsigned short hh = f2bf(f); h4.z = hh; l4.z = f2bf(f - bf2f(hh)); }
                { float f = b4.w; unsigned short hh = f2bf(f); h4.w = hh; l4.w = f2bf(f - bf2f(hh)); }
                *(ush4*)&Bhi[idx] = h4;
                *(ush4*)&Blo[idx] = l4;
            }
            __syncthreads();
            #pragma unroll
            for (int ks = 0; ks < 2; ++ks) {
                short8 ah[4], al[4], bh[4], bl[4];
                const int kk = ks * 32 + lg * 8;
                #pragma unroll
                for (int mi = 0; mi < 4; ++mi) {
                    const int r = wr * 64 + mi * 16 + l15;
                    const int idx = r * BK + (kk ^ ((r & 7) << 3));
                    ah[mi] = *(const short8*)&Ahi[idx];
                    al[mi] = *(const short8*)&Alo[idx];
                }
                #pragma unroll
                for (int ni = 0; ni < 4; ++ni) {
                    const int r = wc * 64 + ni * 16 + l15;
                    const int idx = r * BK + (kk ^ ((r & 7) << 3));
                    bh[ni] = *(const short8*)&Bhi[idx];
                    bl[ni] = *(const short8*)&Blo[idx];
                }
                #pragma unroll
                for (int mi = 0; mi < 4; ++mi)
                    #pragma unroll
                    for (int ni = 0; ni < 4; ++ni) {
                        acc[mi][ni] = __builtin_amdgcn_mfma_f32_16x16x32_bf16(ah[mi], bh[ni], acc[mi][ni], 0, 0, 0);
                        acc[mi][ni] = __builtin_amdgcn_mfma_f32_16x16x32_bf16(ah[mi], bl[ni], acc[mi][ni], 0, 0, 0);
                        acc[mi][ni] = __builtin_amdgcn_mfma_f32_16x16x32_bf16(al[mi], bh[ni], acc[mi][ni], 0, 0, 0);
                    }
            }
        }
        // epilogue: tanh + dot with v, reduce 16 lanes -> row partial
        const float* phb = ph + b * H + nt * 128 + wc * 64;
        const float* vb  = v + nt * 128 + wc * 64;
        #pragma unroll
        for (int mi = 0; mi < 4; ++mi) {
            #pragma unroll
            for (int j = 0; j < 4; ++j) {
                float p = 0.f;
                #pragma unroll
                for (int ni = 0; ni < 4; ++ni) {
                    const int c = ni * 16 + l15;
                    p += vb[c] * tanhf(acc[mi][ni][j] + phb[c]);
                }
                p += __shfl_xor(p, 1); p += __shfl_xor(p, 2);
                p += __shfl_xor(p, 4); p += __shfl_xor(p, 8);
                if (l15 == 0) {
                    const int row = wr * 64 + mi * 16 + lg * 4 + j;
                    slds[wc * 128 + row] += p;   // unique writer per slot
                }
            }
        }
    }
    __syncthreads();
    if (tid < 128) scores[mt * 128 + tid] = slds[tid] + slds[128 + tid];
}

// ---------------- softmax over S per batch ----------------
__global__ __launch_bounds__(256) void softmax_kernel(
    const float* __restrict__ scores, float* __restrict__ attn)
{
    const int b = blockIdx.x, tid = threadIdx.x;
    const float* srow = scores + b * S;
    float x[8];
    float m = -1e30f;
    #pragma unroll
    for (int i = 0; i < 8; ++i) { x[i] = srow[tid + i * 256]; m = fmaxf(m, x[i]); }
    #pragma unroll
    for (int off = 32; off; off >>= 1) m = fmaxf(m, __shfl_xor(m, off));
    __shared__ float wred[4], wsum[4];
    const int w = tid >> 6;
    if ((tid & 63) == 0) wred[w] = m;
    __syncthreads();
    const float M = fmaxf(fmaxf(wred[0], wred[1]), fmaxf(wred[2], wred[3]));
    float s = 0.f;
    #pragma unroll
    for (int i = 0; i < 8; ++i) { x[i] = expf(x[i] - M); s += x[i]; }
    #pragma unroll
    for (int off = 32; off; off >>= 1) s += __shfl_xor(s, off);
    if ((tid & 63) == 0) wsum[w] = s;
    __syncthreads();
    const float inv = 1.f / (wsum[0] + wsum[1] + wsum[2] + wsum[3]);
    #pragma unroll
    for (int i = 0; i < 8; ++i) attn[b * S + tid + i * 256] = x[i] * inv;
}

// ---------------- context partials: part[sc][b][h] ----------------
__global__ __launch_bounds__(256) void ctx_partial(
    const float* __restrict__ enc, const float* __restrict__ attn,
    float* __restrict__ part)
{
    const int sc = blockIdx.x;   // 0..7
    const int b  = blockIdx.y;   // 0..31
    const int tid = threadIdx.x;
    const float* encb = enc + ((size_t)b * S + sc * 256) * H;
    const float* wb = attn + b * S + sc * 256;
    __shared__ float wl[256];
    wl[tid] = wb[tid];
    __syncthreads();
    float4 acc = {0.f, 0.f, 0.f, 0.f};
    for (int s = 0; s < 256; ++s) {
        const float wgt = wl[s];
        const float4 e = *(const float4*)(encb + (size_t)s * H + tid * 4);
        acc.x += wgt * e.x; acc.y += wgt * e.y; acc.z += wgt * e.z; acc.w += wgt * e.w;
    }
    ((float4*)(part + ((size_t)(sc * B + b)) * H))[tid] = acc;
}

__global__ __launch_bounds__(256) void ctx_reduce(
    const float* __restrict__ part, float* __restrict__ ctx)
{
    const int i = blockIdx.x * 256 + threadIdx.x;  // 0..32767
    float s = 0.f;
    #pragma unroll
    for (int sc = 0; sc < 8; ++sc) s += part[(size_t)sc * (B * H) + i];
    ctx[i] = s;
}

extern "C" void kernel_launch(void* const* d_in, const int* in_sizes, int n_in,
                              void* d_out, int out_size, void* d_ws, size_t ws_size,
                              hipStream_t stream) {
    const float* hidden = (const float*)d_in[0];
    const float* enc    = (const float*)d_in[1];
    const float* W      = (const float*)d_in[2];
    const float* b_attn = (const float*)d_in[3];
    const float* v      = (const float*)d_in[4];
    float* ctx  = (float*)d_out;            // (B, H)
    float* attn = ctx + B * H;              // (B, S)
    float* ws      = (float*)d_ws;
    float* scores  = ws;                    // B*S      = 65536
    float* ph      = ws + B * S;            // B*H      = 32768
    float* part    = ws + B * S + B * H;    // 8*B*H    = 262144

    proj_h_kernel<<<dim3(H / 256, B), 256, 0, stream>>>(hidden, W, b_attn, ph);
    score_gemm<<<dim3((B * S) / BM), 256, 0, stream>>>(enc, W, ph, v, scores);
    softmax_kernel<<<dim3(B), 256, 0, stream>>>(scores, attn);
    ctx_partial<<<dim3(8, B), 256, 0, stream>>>(enc, attn, part);
    ctx_reduce<<<dim3((B * H) / 256), 256, 0, stream>>>(part, ctx);
}

// Round 2
// 939.708 us; speedup vs baseline: 1.2304x; 1.2304x over previous
//
#include <hip/hip_runtime.h>
#include <hip/hip_bf16.h>

#define H 1024
#define B 32
#define S 2048

typedef __attribute__((ext_vector_type(8))) _Float16 half8;
typedef __attribute__((ext_vector_type(4))) _Float16 half4;
typedef __attribute__((ext_vector_type(4))) float f32x4;

// ---------------- proj_h = h @ Wh^T + b_attn  (32 x 1024) ----------------
// One wave per output o: lanes stride W[o] row contiguously (coalesced 256B).
__global__ __launch_bounds__(256) void proj_h_kernel(
    const float* __restrict__ hidden, const float* __restrict__ W,
    const float* __restrict__ b_attn, float* __restrict__ ph)
{
    const int b = blockIdx.y;
    const int tid = threadIdx.x;
    __shared__ float hs[H];
    const float4* hr = (const float4*)(hidden + (size_t)(B + b) * H); // hidden[-1]
    ((float4*)hs)[tid] = hr[tid];
    __syncthreads();
    const int w = tid >> 6, lane = tid & 63;
    const int o = blockIdx.x * 4 + w;
    const float* wr = W + (size_t)o * (2 * H);   // Wh row o (cols 0..H-1)
    float acc = 0.f;
    #pragma unroll
    for (int i = 0; i < 16; ++i) {
        const int k = i * 64 + lane;
        acc += wr[k] * hs[k];
    }
    #pragma unroll
    for (int off = 32; off; off >>= 1) acc += __shfl_xor(acc, off);
    if (lane == 0) ph[b * H + o] = acc + b_attn[o];
}

// ------- fused scores: scores[b,s] = sum_o v[o]*tanh(enc@We^T + ph) -------
// Single-pass fp16 MFMA (fp32 accumulate). Block: 4 waves (2x2), BM=128.
#define BM 128
#define BK 64
__global__ __launch_bounds__(256, 4) void score_gemm(
    const float* __restrict__ enc, const float* __restrict__ W,
    const float* __restrict__ ph, const float* __restrict__ v,
    float* __restrict__ scores)
{
    __shared__ _Float16 Ah[BM * BK], Bh[BM * BK];
    __shared__ float slds[256];
    const int tid  = threadIdx.x;
    const int mt   = blockIdx.x;            // 0..511
    const int lane = tid & 63;
    const int wid  = tid >> 6;
    const int wr   = wid >> 1, wc = wid & 1;
    const int l15  = lane & 15, lg = lane >> 4;
    const int b    = mt >> 4;               // 16 M-tiles per batch
    const float* encM = enc + (size_t)mt * BM * H;

    slds[tid] = 0.f;
    const int sc4   = (tid & 15) * 4;       // k-offset (halfs) this thread stages
    const int rbase = tid >> 4;

    for (int nt = 0; nt < 8; ++nt) {
        f32x4 acc[4][4];
        #pragma unroll
        for (int mi = 0; mi < 4; ++mi)
            #pragma unroll
            for (int ni = 0; ni < 4; ++ni) acc[mi][ni] = (f32x4){0.f, 0.f, 0.f, 0.f};

        const float* Wn = W + (size_t)(nt * 128) * (2 * H) + H;  // We rows, this N-chunk

        for (int kt = 0; kt < H / BK; ++kt) {
            __syncthreads();
            const int k0 = kt * BK;
            #pragma unroll
            for (int i = 0; i < 8; ++i) {
                const int row = i * 16 + rbase;
                const int idx = row * BK + (sc4 ^ ((row & 7) << 3)); // XOR swizzle (16B slots)
                float4 a4 = *(const float4*)(encM + (size_t)row * H + k0 + sc4);
                *(half4*)&Ah[idx] = (half4){(_Float16)a4.x, (_Float16)a4.y,
                                            (_Float16)a4.z, (_Float16)a4.w};
                float4 b4 = *(const float4*)(Wn + (size_t)row * (2 * H) + k0 + sc4);
                *(half4*)&Bh[idx] = (half4){(_Float16)b4.x, (_Float16)b4.y,
                                            (_Float16)b4.z, (_Float16)b4.w};
            }
            __syncthreads();
            #pragma unroll
            for (int ks = 0; ks < 2; ++ks) {
                half8 ah[4], bh[4];
                const int kk = ks * 32 + lg * 8;
                #pragma unroll
                for (int mi = 0; mi < 4; ++mi) {
                    const int r = wr * 64 + mi * 16 + l15;
                    ah[mi] = *(const half8*)&Ah[r * BK + (kk ^ ((r & 7) << 3))];
                }
                #pragma unroll
                for (int ni = 0; ni < 4; ++ni) {
                    const int r = wc * 64 + ni * 16 + l15;
                    bh[ni] = *(const half8*)&Bh[r * BK + (kk ^ ((r & 7) << 3))];
                }
                #pragma unroll
                for (int mi = 0; mi < 4; ++mi)
                    #pragma unroll
                    for (int ni = 0; ni < 4; ++ni)
                        acc[mi][ni] = __builtin_amdgcn_mfma_f32_16x16x32_f16(
                            ah[mi], bh[ni], acc[mi][ni], 0, 0, 0);
            }
        }
        // epilogue: tanh + dot with v, reduce 16 lanes -> row partial
        const float* phb = ph + b * H + nt * 128 + wc * 64;
        const float* vb  = v + nt * 128 + wc * 64;
        #pragma unroll
        for (int mi = 0; mi < 4; ++mi) {
            #pragma unroll
            for (int j = 0; j < 4; ++j) {
                float p = 0.f;
                #pragma unroll
                for (int ni = 0; ni < 4; ++ni) {
                    const int c = ni * 16 + l15;
                    p += vb[c] * tanhf(acc[mi][ni][j] + phb[c]);
                }
                p += __shfl_xor(p, 1); p += __shfl_xor(p, 2);
                p += __shfl_xor(p, 4); p += __shfl_xor(p, 8);
                if (l15 == 0) {
                    const int row = wr * 64 + mi * 16 + lg * 4 + j;
                    slds[wc * 128 + row] += p;   // unique writer per slot
                }
            }
        }
    }
    __syncthreads();
    if (tid < 128) scores[mt * 128 + tid] = slds[tid] + slds[128 + tid];
}

// ---------------- softmax over S per batch ----------------
__global__ __launch_bounds__(256) void softmax_kernel(
    const float* __restrict__ scores, float* __restrict__ attn)
{
    const int b = blockIdx.x, tid = threadIdx.x;
    const float* srow = scores + b * S;
    float x[8];
    float m = -1e30f;
    #pragma unroll
    for (int i = 0; i < 8; ++i) { x[i] = srow[tid + i * 256]; m = fmaxf(m, x[i]); }
    #pragma unroll
    for (int off = 32; off; off >>= 1) m = fmaxf(m, __shfl_xor(m, off));
    __shared__ float wred[4], wsum[4];
    const int w = tid >> 6;
    if ((tid & 63) == 0) wred[w] = m;
    __syncthreads();
    const float M = fmaxf(fmaxf(wred[0], wred[1]), fmaxf(wred[2], wred[3]));
    float s = 0.f;
    #pragma unroll
    for (int i = 0; i < 8; ++i) { x[i] = expf(x[i] - M); s += x[i]; }
    #pragma unroll
    for (int off = 32; off; off >>= 1) s += __shfl_xor(s, off);
    if ((tid & 63) == 0) wsum[w] = s;
    __syncthreads();
    const float inv = 1.f / (wsum[0] + wsum[1] + wsum[2] + wsum[3]);
    #pragma unroll
    for (int i = 0; i < 8; ++i) attn[b * S + tid + i * 256] = x[i] * inv;
}

// ---------------- context partials: part[sc][b][h] ----------------
__global__ __launch_bounds__(256) void ctx_partial(
    const float* __restrict__ enc, const float* __restrict__ attn,
    float* __restrict__ part)
{
    const int sc = blockIdx.x;   // 0..7
    const int b  = blockIdx.y;   // 0..31
    const int tid = threadIdx.x;
    const float* encb = enc + ((size_t)b * S + sc * 256) * H;
    const float* wb = attn + b * S + sc * 256;
    __shared__ float wl[256];
    wl[tid] = wb[tid];
    __syncthreads();
    float4 acc = {0.f, 0.f, 0.f, 0.f};
    for (int s = 0; s < 256; ++s) {
        const float wgt = wl[s];
        const float4 e = *(const float4*)(encb + (size_t)s * H + tid * 4);
        acc.x += wgt * e.x; acc.y += wgt * e.y; acc.z += wgt * e.z; acc.w += wgt * e.w;
    }
    ((float4*)(part + ((size_t)(sc * B + b)) * H))[tid] = acc;
}

__global__ __launch_bounds__(256) void ctx_reduce(
    const float* __restrict__ part, float* __restrict__ ctx)
{
    const int i = blockIdx.x * 256 + threadIdx.x;  // 0..32767
    float s = 0.f;
    #pragma unroll
    for (int sc = 0; sc < 8; ++sc) s += part[(size_t)sc * (B * H) + i];
    ctx[i] = s;
}

extern "C" void kernel_launch(void* const* d_in, const int* in_sizes, int n_in,
                              void* d_out, int out_size, void* d_ws, size_t ws_size,
                              hipStream_t stream) {
    const float* hidden = (const float*)d_in[0];
    const float* enc    = (const float*)d_in[1];
    const float* W      = (const float*)d_in[2];
    const float* b_attn = (const float*)d_in[3];
    const float* v      = (const float*)d_in[4];
    float* ctx  = (float*)d_out;            // (B, H)
    float* attn = ctx + B * H;              // (B, S)
    float* ws      = (float*)d_ws;
    float* scores  = ws;                    // B*S      = 65536
    float* ph      = ws + B * S;            // B*H      = 32768
    float* part    = ws + B * S + B * H;    // 8*B*H    = 262144

    proj_h_kernel<<<dim3(H / 4, B), 256, 0, stream>>>(hidden, W, b_attn, ph);
    score_gemm<<<dim3((B * S) / BM), 256, 0, stream>>>(enc, W, ph, v, scores);
    softmax_kernel<<<dim3(B), 256, 0, stream>>>(scores, attn);
    ctx_partial<<<dim3(8, B), 256, 0, stream>>>(enc, attn, part);
    ctx_reduce<<<dim3((B * H) / 256), 256, 0, stream>>>(part, ctx);
}

// Round 3
// 487.141 us; speedup vs baseline: 2.3734x; 1.9290x over previous
//
#include <hip/hip_runtime.h>
#include <hip/hip_bf16.h>

#define H 1024
#define B 32
#define S 2048

typedef __attribute__((ext_vector_type(8))) _Float16 h8;
typedef __attribute__((ext_vector_type(4))) _Float16 h4;
typedef __attribute__((ext_vector_type(8))) short short8;
typedef __attribute__((ext_vector_type(4))) float f32x4;

__device__ __forceinline__ float fast_tanh(float x) {
    float a = __builtin_fabsf(x);
    float e = __expf(2.0f * a);
    float r = 1.0f - 2.0f / (e + 1.0f);   // == tanh(a), exact formula
    return __builtin_copysignf(r, x);
}

__device__ __forceinline__ void gload_lds16(const void* g, void* l) {
    __builtin_amdgcn_global_load_lds(
        (const __attribute__((address_space(1))) unsigned int*)g,
        (__attribute__((address_space(3))) unsigned int*)l, 16, 0, 0);
}

// ---------------- proj_h = h @ Wh^T + b_attn  (32 x 1024) ----------------
__global__ __launch_bounds__(256) void proj_h_kernel(
    const float* __restrict__ hidden, const float* __restrict__ W,
    const float* __restrict__ b_attn, float* __restrict__ ph)
{
    const int b = blockIdx.y;
    const int tid = threadIdx.x;
    __shared__ float hs[H];
    const float4* hr = (const float4*)(hidden + (size_t)(B + b) * H); // hidden[-1]
    ((float4*)hs)[tid] = hr[tid];
    __syncthreads();
    const int w = tid >> 6, lane = tid & 63;
    const int o = blockIdx.x * 4 + w;
    const float* wr = W + (size_t)o * (2 * H);
    float acc = 0.f;
    #pragma unroll
    for (int i = 0; i < 16; ++i) {
        const int k = i * 64 + lane;
        acc += wr[k] * hs[k];
    }
    #pragma unroll
    for (int off = 32; off; off >>= 1) acc += __shfl_xor(acc, off);
    if (lane == 0) ph[b * H + o] = acc + b_attn[o];
}

// ---------------- We (f32) -> We_h (fp16), row-major [1024][1024] --------
__global__ __launch_bounds__(256) void conv_We(
    const float* __restrict__ W, _Float16* __restrict__ We_h)
{
    const int o = blockIdx.x;            // 0..1023
    const int t = threadIdx.x;
    float4 f = *(const float4*)(W + (size_t)o * 2048 + 1024 + t * 4);
    h4 hv = {(_Float16)f.x, (_Float16)f.y, (_Float16)f.z, (_Float16)f.w};
    *(h4*)(We_h + (size_t)o * 1024 + t * 4) = hv;
}

// ------- fused scores v3: A-panel-in-LDS + global_load_lds B pipeline ----
// BM=64 rows/block, BN=128 per nt (8 nt), BK=32. 4 waves 2x2 (32x64 tiles).
#define LDS_A   0          // 64 rows x 2048B fp16 (swizzled 16B slots)
#define LDS_B   131072     // 2 x 8192B tiles (128 n-rows x 64B, swizzled)
#define LDS_PH  147456     // 1024 f32
#define LDS_V   151552     // 1024 f32
#define LDS_S   155648     // 256 f32 score partials
#define LDS_TOT 156672

__global__ __launch_bounds__(256) void score_v3(
    const float* __restrict__ enc, const _Float16* __restrict__ We_h,
    const float* __restrict__ ph, const float* __restrict__ v,
    float* __restrict__ scores)
{
    extern __shared__ __align__(16) char smem[];
    float* phs  = (float*)(smem + LDS_PH);
    float* vls  = (float*)(smem + LDS_V);
    float* slds = (float*)(smem + LDS_S);

    const int tid = threadIdx.x;
    const int mt  = blockIdx.x;          // 0..1023
    const int b   = mt >> 5;
    const int lane = tid & 63;
    const int wid  = tid >> 6;
    const int wr = wid >> 1, wc = wid & 1;
    const int l15 = lane & 15, lg = lane >> 4;
    const float* encM = enc + (size_t)mt * 64 * H;

    // ---- prologue ----
    slds[tid] = 0.f;
    {   // ph row + v into LDS
        *(float4*)(phs + tid * 4) = *(const float4*)(ph + b * H + tid * 4);
        *(float4*)(vls + tid * 4) = *(const float4*)(v + tid * 4);
    }
    const int stg_ksrc = (((lane & 3) ^ ((lane >> 2) & 3)) << 3); // halfs
    const int stg_r0   = (wid * 2) * 16 + (lane >> 2);
    const int stg_r1   = (wid * 2 + 1) * 16 + (lane >> 2);
    {   // stage B tile it=0 into buf0 (issue early, lands under A-convert)
        gload_lds16(We_h + (size_t)stg_r0 * H + stg_ksrc, smem + LDS_B + (wid * 2) * 1024);
        gload_lds16(We_h + (size_t)stg_r1 * H + stg_ksrc, smem + LDS_B + (wid * 2 + 1) * 1024);
    }
    {   // convert A panel: 64 rows x 1024 f32 -> fp16 swizzled
        const int r = tid >> 2, q = tid & 3;
        const int swz = (r & 7) << 4;
        const float* arow = encM + (size_t)r * H;
        char* Arow = smem + LDS_A + r * 2048;
        #pragma unroll 4
        for (int i = 0; i < 32; ++i) {
            const int s = q + i * 4;                 // 16B slot index 0..127
            float4 f0 = *(const float4*)(arow + s * 8);
            float4 f1 = *(const float4*)(arow + s * 8 + 4);
            h8 hv = {(_Float16)f0.x, (_Float16)f0.y, (_Float16)f0.z, (_Float16)f0.w,
                     (_Float16)f1.x, (_Float16)f1.y, (_Float16)f1.z, (_Float16)f1.w};
            *(h8*)(Arow + ((s * 16) ^ swz)) = hv;
        }
    }
    __syncthreads();

    // ---- precomputed frag offsets ----
    const int klg = lg * 16;                         // k-slice byte offset
    int baseA[2], swzA[2];
    #pragma unroll
    for (int mi = 0; mi < 2; ++mi) {
        const int r = wr * 32 + mi * 16 + l15;
        baseA[mi] = r * 2048;
        swzA[mi]  = (r & 7) << 4;
    }
    int offB[4];
    #pragma unroll
    for (int ni = 0; ni < 4; ++ni) {
        const int n = wc * 64 + ni * 16 + l15;
        offB[ni] = LDS_B + n * 64 + (klg ^ ((n & 3) << 4));
    }
    float* scout = scores + mt * 64;

    for (int nt = 0; nt < 8; ++nt) {
        f32x4 acc[2][4];
        #pragma unroll
        for (int mi = 0; mi < 2; ++mi)
            #pragma unroll
            for (int ni = 0; ni < 4; ++ni) acc[mi][ni] = (f32x4){0.f, 0.f, 0.f, 0.f};

        #define KBODY(KP, CUR)                                                          \
        {                                                                               \
            const int it = nt * 32 + (KP);                                              \
            if (it < 255) {  /* stage next tile into other buffer */                    \
                const size_t tb = (size_t)((it + 1) >> 5) * (128 * H)                   \
                                + (size_t)((it + 1) & 31) * 32;                         \
                char* dstb = smem + LDS_B + ((CUR) ^ 1) * 8192;                         \
                gload_lds16(We_h + tb + (size_t)stg_r0 * H + stg_ksrc, dstb + (wid * 2) * 1024);     \
                gload_lds16(We_h + tb + (size_t)stg_r1 * H + stg_ksrc, dstb + (wid * 2 + 1) * 1024); \
            }                                                                           \
            const int kb = (KP) << 6;                                                   \
            h8 ah[2], bh[4];                                                            \
            _Pragma("unroll")                                                           \
            for (int mi = 0; mi < 2; ++mi)                                              \
                ah[mi] = *(const h8*)(smem + LDS_A + baseA[mi] + ((kb | klg) ^ swzA[mi])); \
            _Pragma("unroll")                                                           \
            for (int ni = 0; ni < 4; ++ni)                                              \
                bh[ni] = *(const h8*)(smem + offB[ni] + (CUR) * 8192);                  \
            _Pragma("unroll")                                                           \
            for (int mi = 0; mi < 2; ++mi)                                              \
                _Pragma("unroll")                                                       \
                for (int ni = 0; ni < 4; ++ni)                                          \
                    acc[mi][ni] = __builtin_amdgcn_mfma_f32_16x16x32_f16(               \
                        ah[mi], bh[ni], acc[mi][ni], 0, 0, 0);                          \
            __syncthreads();                                                            \
        }

        for (int kp2 = 0; kp2 < 16; ++kp2) {
            KBODY(2 * kp2, 0)
            KBODY(2 * kp2 + 1, 1)
        }
        #undef KBODY

        // epilogue: tanh + v-dot, per-row partials into wave-private slds
        const int colb = nt * 128 + wc * 64;
        float vreg[4], preg[4];
        #pragma unroll
        for (int ni = 0; ni < 4; ++ni) {
            const int c = colb + ni * 16 + l15;
            vreg[ni] = vls[c];
            preg[ni] = phs[c];
        }
        #pragma unroll
        for (int mi = 0; mi < 2; ++mi) {
            #pragma unroll
            for (int j = 0; j < 4; ++j) {
                float p = 0.f;
                #pragma unroll
                for (int ni = 0; ni < 4; ++ni)
                    p += vreg[ni] * fast_tanh(acc[mi][ni][j] + preg[ni]);
                p += __shfl_xor(p, 1); p += __shfl_xor(p, 2);
                p += __shfl_xor(p, 4); p += __shfl_xor(p, 8);
                if (l15 == 0)
                    slds[wid * 64 + wr * 32 + mi * 16 + lg * 4 + j] += p;
            }
        }
    }
    __syncthreads();
    if (tid < 64)
        scout[tid] = slds[tid] + slds[64 + tid] + slds[128 + tid] + slds[192 + tid];
}

// ---------------- fallback score (R2 path, known-good) ----------------
#define BM 128
#define BK 64
__global__ __launch_bounds__(256, 4) void score_old(
    const float* __restrict__ enc, const float* __restrict__ W,
    const float* __restrict__ ph, const float* __restrict__ v,
    float* __restrict__ scores)
{
    __shared__ _Float16 Ah[BM * BK], Bh[BM * BK];
    __shared__ float slds[256];
    const int tid  = threadIdx.x;
    const int mt   = blockIdx.x;
    const int lane = tid & 63;
    const int wid  = tid >> 6;
    const int wr   = wid >> 1, wc = wid & 1;
    const int l15  = lane & 15, lg = lane >> 4;
    const int b    = mt >> 4;
    const float* encM = enc + (size_t)mt * BM * H;
    slds[tid] = 0.f;
    const int sc4   = (tid & 15) * 4;
    const int rbase = tid >> 4;
    for (int nt = 0; nt < 8; ++nt) {
        f32x4 acc[4][4];
        #pragma unroll
        for (int mi = 0; mi < 4; ++mi)
            #pragma unroll
            for (int ni = 0; ni < 4; ++ni) acc[mi][ni] = (f32x4){0.f, 0.f, 0.f, 0.f};
        const float* Wn = W + (size_t)(nt * 128) * (2 * H) + H;
        for (int kt = 0; kt < H / BK; ++kt) {
            __syncthreads();
            const int k0 = kt * BK;
            #pragma unroll
            for (int i = 0; i < 8; ++i) {
                const int row = i * 16 + rbase;
                const int idx = row * BK + (sc4 ^ ((row & 7) << 3));
                float4 a4 = *(const float4*)(encM + (size_t)row * H + k0 + sc4);
                *(h4*)&Ah[idx] = (h4){(_Float16)a4.x, (_Float16)a4.y, (_Float16)a4.z, (_Float16)a4.w};
                float4 b4 = *(const float4*)(Wn + (size_t)row * (2 * H) + k0 + sc4);
                *(h4*)&Bh[idx] = (h4){(_Float16)b4.x, (_Float16)b4.y, (_Float16)b4.z, (_Float16)b4.w};
            }
            __syncthreads();
            #pragma unroll
            for (int ks = 0; ks < 2; ++ks) {
                h8 ah[4], bh[4];
                const int kk = ks * 32 + lg * 8;
                #pragma unroll
                for (int mi = 0; mi < 4; ++mi) {
                    const int r = wr * 64 + mi * 16 + l15;
                    ah[mi] = *(const h8*)&Ah[r * BK + (kk ^ ((r & 7) << 3))];
                }
                #pragma unroll
                for (int ni = 0; ni < 4; ++ni) {
                    const int r = wc * 64 + ni * 16 + l15;
                    bh[ni] = *(const h8*)&Bh[r * BK + (kk ^ ((r & 7) << 3))];
                }
                #pragma unroll
                for (int mi = 0; mi < 4; ++mi)
                    #pragma unroll
                    for (int ni = 0; ni < 4; ++ni)
                        acc[mi][ni] = __builtin_amdgcn_mfma_f32_16x16x32_f16(
                            ah[mi], bh[ni], acc[mi][ni], 0, 0, 0);
            }
        }
        const float* phb = ph + b * H + nt * 128 + wc * 64;
        const float* vb  = v + nt * 128 + wc * 64;
        #pragma unroll
        for (int mi = 0; mi < 4; ++mi) {
            #pragma unroll
            for (int j = 0; j < 4; ++j) {
                float p = 0.f;
                #pragma unroll
                for (int ni = 0; ni < 4; ++ni) {
                    const int c = ni * 16 + l15;
                    p += vb[c] * fast_tanh(acc[mi][ni][j] + phb[c]);
                }
                p += __shfl_xor(p, 1); p += __shfl_xor(p, 2);
                p += __shfl_xor(p, 4); p += __shfl_xor(p, 8);
                if (l15 == 0) {
                    const int row = wr * 64 + mi * 16 + lg * 4 + j;
                    slds[wc * 128 + row] += p;
                }
            }
        }
    }
    __syncthreads();
    if (tid < 128) scores[mt * 128 + tid] = slds[tid] + slds[128 + tid];
}

// ---------------- softmax over S per batch ----------------
__global__ __launch_bounds__(256) void softmax_kernel(
    const float* __restrict__ scores, float* __restrict__ attn)
{
    const int b = blockIdx.x, tid = threadIdx.x;
    const float* srow = scores + b * S;
    float x[8];
    float m = -1e30f;
    #pragma unroll
    for (int i = 0; i < 8; ++i) { x[i] = srow[tid + i * 256]; m = fmaxf(m, x[i]); }
    #pragma unroll
    for (int off = 32; off; off >>= 1) m = fmaxf(m, __shfl_xor(m, off));
    __shared__ float wred[4], wsum[4];
    const int w = tid >> 6;
    if ((tid & 63) == 0) wred[w] = m;
    __syncthreads();
    const float M = fmaxf(fmaxf(wred[0], wred[1]), fmaxf(wred[2], wred[3]));
    float s = 0.f;
    #pragma unroll
    for (int i = 0; i < 8; ++i) { x[i] = expf(x[i] - M); s += x[i]; }
    #pragma unroll
    for (int off = 32; off; off >>= 1) s += __shfl_xor(s, off);
    if ((tid & 63) == 0) wsum[w] = s;
    __syncthreads();
    const float inv = 1.f / (wsum[0] + wsum[1] + wsum[2] + wsum[3]);
    #pragma unroll
    for (int i = 0; i < 8; ++i) attn[b * S + tid + i * 256] = x[i] * inv;
}

// ---------------- context: partial over S-chunks, then reduce ----------------
__global__ __launch_bounds__(256) void ctx_partial(
    const float* __restrict__ enc, const float* __restrict__ attn,
    float* __restrict__ part, int rows)
{
    const int sc = blockIdx.x;
    const int b  = blockIdx.y;
    const int tid = threadIdx.x;
    const float* encb = enc + ((size_t)b * S + (size_t)sc * rows) * H;
    const float* wb = attn + b * S + sc * rows;
    __shared__ float wl[256];
    if (tid < rows) wl[tid] = wb[tid];
    __syncthreads();
    float4 acc = {0.f, 0.f, 0.f, 0.f};
    for (int s = 0; s < rows; ++s) {
        const float wgt = wl[s];
        const float4 e = *(const float4*)(encb + (size_t)s * H + tid * 4);
        acc.x += wgt * e.x; acc.y += wgt * e.y; acc.z += wgt * e.z; acc.w += wgt * e.w;
    }
    ((float4*)(part + ((size_t)(sc * B + b)) * H))[tid] = acc;
}

__global__ __launch_bounds__(256) void ctx_reduce(
    const float* __restrict__ part, float* __restrict__ ctx, int nch)
{
    const int i = blockIdx.x * 256 + threadIdx.x;
    float s = 0.f;
    for (int c = 0; c < nch; ++c) s += part[(size_t)c * (B * H) + i];
    ctx[i] = s;
}

extern "C" void kernel_launch(void* const* d_in, const int* in_sizes, int n_in,
                              void* d_out, int out_size, void* d_ws, size_t ws_size,
                              hipStream_t stream) {
    const float* hidden = (const float*)d_in[0];
    const float* enc    = (const float*)d_in[1];
    const float* W      = (const float*)d_in[2];
    const float* b_attn = (const float*)d_in[3];
    const float* v      = (const float*)d_in[4];
    float* ctx  = (float*)d_out;            // (B, H)
    float* attn = ctx + B * H;              // (B, S)
    float* ws      = (float*)d_ws;
    float* scores  = ws;                    // 65536 f32
    float* ph      = ws + B * S;            // 32768 f32
    float* region  = ws + B * S + B * H;    // union: We_h (2MB) then part16 (2MB)

    const size_t need = (size_t)(B * S + B * H + 16 * B * H) * 4;

    proj_h_kernel<<<dim3(H / 4, B), 256, 0, stream>>>(hidden, W, b_attn, ph);

    if (ws_size >= need) {
        _Float16* We_h = (_Float16*)region;
        float* part = region;               // reused after score_v3 consumed We_h
        conv_We<<<1024, 256, 0, stream>>>(W, We_h);
        hipFuncSetAttribute((const void*)score_v3,
                            hipFuncAttributeMaxDynamicSharedMemorySize, LDS_TOT);
        score_v3<<<1024, 256, LDS_TOT, stream>>>(enc, We_h, ph, v, scores);
        softmax_kernel<<<dim3(B), 256, 0, stream>>>(scores, attn);
        ctx_partial<<<dim3(16, B), 256, 0, stream>>>(enc, attn, part, 128);
        ctx_reduce<<<dim3((B * H) / 256), 256, 0, stream>>>(part, ctx, 16);
    } else {
        float* part = region;               // 8*B*H fits the R2-size ws
        score_old<<<dim3((B * S) / BM), 256, 0, stream>>>(enc, W, ph, v, scores);
        softmax_kernel<<<dim3(B), 256, 0, stream>>>(scores, attn);
        ctx_partial<<<dim3(8, B), 256, 0, stream>>>(enc, attn, part, 256);
        ctx_reduce<<<dim3((B * H) / 256), 256, 0, stream>>>(part, ctx, 8);
    }
}

// Round 4
// 313.015 us; speedup vs baseline: 3.6937x; 1.5563x over previous
//
#include <hip/hip_runtime.h>
#include <hip/hip_bf16.h>

#define H 1024
#define B 32
#define S 2048

typedef __attribute__((ext_vector_type(8))) _Float16 h8;
typedef __attribute__((ext_vector_type(4))) _Float16 h4;
typedef __attribute__((ext_vector_type(4))) float f32x4;

__device__ __forceinline__ float fast_tanh(float x) {
    float a = __builtin_fabsf(x);
    float e = __expf(2.0f * a);
    float r = 1.0f - 2.0f / (e + 1.0f);   // == tanh(a)
    return __builtin_copysignf(r, x);
}

__device__ __forceinline__ void gload_lds16(const void* g, void* l) {
    __builtin_amdgcn_global_load_lds(
        (const __attribute__((address_space(1))) unsigned int*)g,
        (__attribute__((address_space(3))) unsigned int*)l, 16, 0, 0);
}

// ---------------- proj_h = h @ Wh^T + b_attn  (32 x 1024) ----------------
__global__ __launch_bounds__(256) void proj_h_kernel(
    const float* __restrict__ hidden, const float* __restrict__ W,
    const float* __restrict__ b_attn, float* __restrict__ ph)
{
    const int b = blockIdx.y;
    const int tid = threadIdx.x;
    __shared__ float hs[H];
    const float4* hr = (const float4*)(hidden + (size_t)(B + b) * H); // hidden[-1]
    ((float4*)hs)[tid] = hr[tid];
    __syncthreads();
    const int w = tid >> 6, lane = tid & 63;
    const int o = blockIdx.x * 4 + w;
    const float* wr = W + (size_t)o * (2 * H);
    float acc = 0.f;
    #pragma unroll
    for (int i = 0; i < 16; ++i) {
        const int k = i * 64 + lane;
        acc += wr[k] * hs[k];
    }
    #pragma unroll
    for (int off = 32; off; off >>= 1) acc += __shfl_xor(acc, off);
    if (lane == 0) ph[b * H + o] = acc + b_attn[o];
}

// ---------------- We (f32) -> We_h (fp16), row-major [1024][1024] --------
__global__ __launch_bounds__(256) void conv_We(
    const float* __restrict__ W, _Float16* __restrict__ We_h)
{
    const int o = blockIdx.x;
    const int t = threadIdx.x;
    float4 f = *(const float4*)(W + (size_t)o * 2048 + 1024 + t * 4);
    h4 hv = {(_Float16)f.x, (_Float16)f.y, (_Float16)f.z, (_Float16)f.w};
    *(h4*)(We_h + (size_t)o * 1024 + t * 4) = hv;
}

// ------- score GEMM v4: 128x128 tile, grid 512(M) x 8(N), XCD-swizzled ---
// partial[nb][m] = sum over this block's 128 N-cols of v*tanh(C + ph).
// A: reg-staged f32->fp16 (conflict-free swizzled writes).
// B: B_FP16 ? global_load_lds from We_h : reg-staged from f32 W.
template<bool B_FP16>
__global__ __launch_bounds__(256) void score_v4(
    const float* __restrict__ enc, const void* __restrict__ Bsrc,
    const float* __restrict__ ph, const float* __restrict__ v,
    float* __restrict__ partial)
{
    __shared__ _Float16 As[128 * 64];   // [row][64 halfs], slots XOR (row&7)
    __shared__ _Float16 Bs[128 * 64];
    __shared__ float slds[256];

    const int tid = threadIdx.x;
    const int bid = blockIdx.x;
    // XCD swizzle: 8 N-blocks of one M-panel land on one XCD (bid%8 heuristic)
    const int x  = bid & 7;
    const int ii = bid >> 3;
    const int nb = ii & 7;
    const int mt = (ii >> 3) * 8 + x;      // 0..511
    const int b  = mt >> 4;

    const int lane = tid & 63;
    const int wid  = tid >> 6;
    const int wm = wid >> 1, wn = wid & 1;
    const int l15 = lane & 15, lg = lane >> 4;

    const int arow  = tid >> 3;            // 0..31 (row within 32-row pass)
    const int aslot = tid & 7;             // global 16B k-slot this thread stages
    const int brow_rnd = wid * 8 + (lane >> 3);
    const int bslot    = lane & 7;

    f32x4 acc[4][4];
    #pragma unroll
    for (int mi = 0; mi < 4; ++mi)
        #pragma unroll
        for (int ni = 0; ni < 4; ++ni) acc[mi][ni] = (f32x4){0.f, 0.f, 0.f, 0.f};

    for (int kt = 0; kt < 16; ++kt) {
        const int k0 = kt * 64;            // in elements (halfs == floats count)
        if (B_FP16) {
            // issue B DMA first: latency hides under A convert
            const _Float16* Wh = (const _Float16*)Bsrc;
            #pragma unroll
            for (int q = 0; q < 4; ++q) {
                const int n  = q * 32 + brow_rnd;
                const int gn = nb * 128 + n;
                gload_lds16(Wh + (size_t)gn * H + k0 + ((bslot ^ (n & 7)) * 8),
                            (char*)Bs + (q * 32 + wid * 8) * 128);
            }
        }
        // stage A: 4 passes x (32B f32 load -> cvt -> one b128 LDS write)
        #pragma unroll
        for (int p = 0; p < 4; ++p) {
            const int m = p * 32 + arow;
            const float* src = enc + (size_t)(mt * 128 + m) * H + k0 + aslot * 8;
            float4 f0 = *(const float4*)src;
            float4 f1 = *(const float4*)(src + 4);
            h8 hv = {(_Float16)f0.x, (_Float16)f0.y, (_Float16)f0.z, (_Float16)f0.w,
                     (_Float16)f1.x, (_Float16)f1.y, (_Float16)f1.z, (_Float16)f1.w};
            *(h8*)((char*)As + m * 128 + ((aslot ^ (m & 7)) * 16)) = hv;
        }
        if (!B_FP16) {
            const float* Wf = (const float*)Bsrc;
            #pragma unroll
            for (int p = 0; p < 4; ++p) {
                const int n  = p * 32 + arow;
                const int gn = nb * 128 + n;
                const float* src = Wf + (size_t)gn * 2048 + 1024 + k0 + aslot * 8;
                float4 f0 = *(const float4*)src;
                float4 f1 = *(const float4*)(src + 4);
                h8 hv = {(_Float16)f0.x, (_Float16)f0.y, (_Float16)f0.z, (_Float16)f0.w,
                         (_Float16)f1.x, (_Float16)f1.y, (_Float16)f1.z, (_Float16)f1.w};
                *(h8*)((char*)Bs + n * 128 + ((aslot ^ (n & 7)) * 16)) = hv;
            }
        }
        __syncthreads();                    // drains vmcnt (gload_lds) + lgkm
        #pragma unroll
        for (int ks = 0; ks < 2; ++ks) {
            h8 ah[4], bh[4];
            const int sl = ks * 4 + lg;     // k 16B-slot this lane consumes
            #pragma unroll
            for (int mi = 0; mi < 4; ++mi) {
                const int r = wm * 64 + mi * 16 + l15;
                ah[mi] = *(const h8*)((char*)As + r * 128 + 16 * (sl ^ (r & 7)));
            }
            #pragma unroll
            for (int ni = 0; ni < 4; ++ni) {
                const int r = wn * 64 + ni * 16 + l15;
                bh[ni] = *(const h8*)((char*)Bs + r * 128 + 16 * (sl ^ (r & 7)));
            }
            #pragma unroll
            for (int mi = 0; mi < 4; ++mi)
                #pragma unroll
                for (int ni = 0; ni < 4; ++ni)
                    acc[mi][ni] = __builtin_amdgcn_mfma_f32_16x16x32_f16(
                        ah[mi], bh[ni], acc[mi][ni], 0, 0, 0);
        }
        __syncthreads();
    }

    // epilogue: tanh + v-dot over this block's 128 cols -> per-row partial
    float vreg[4], preg[4];
    #pragma unroll
    for (int ni = 0; ni < 4; ++ni) {
        const int gcol = nb * 128 + wn * 64 + ni * 16 + l15;
        vreg[ni] = v[gcol];
        preg[ni] = ph[b * H + gcol];
    }
    #pragma unroll
    for (int mi = 0; mi < 4; ++mi) {
        #pragma unroll
        for (int j = 0; j < 4; ++j) {
            float p = 0.f;
            #pragma unroll
            for (int ni = 0; ni < 4; ++ni)
                p += vreg[ni] * fast_tanh(acc[mi][ni][j] + preg[ni]);
            p += __shfl_xor(p, 1); p += __shfl_xor(p, 2);
            p += __shfl_xor(p, 4); p += __shfl_xor(p, 8);
            if (l15 == 0)
                slds[wn * 128 + wm * 64 + mi * 16 + lg * 4 + j] = p;
        }
    }
    __syncthreads();
    if (tid < 128)
        partial[(size_t)nb * (B * S) + mt * 128 + tid] = slds[tid] + slds[128 + tid];
}

// ---------------- softmax over S per batch (sums the 8 N-partials) -------
__global__ __launch_bounds__(256) void softmax_kernel(
    const float* __restrict__ partial, float* __restrict__ attn)
{
    const int b = blockIdx.x, tid = threadIdx.x;
    float xv[8];
    float m = -1e30f;
    #pragma unroll
    for (int i = 0; i < 8; ++i) {
        float s = 0.f;
        #pragma unroll
        for (int nb = 0; nb < 8; ++nb)
            s += partial[(size_t)nb * (B * S) + b * S + tid + i * 256];
        xv[i] = s;
        m = fmaxf(m, s);
    }
    #pragma unroll
    for (int off = 32; off; off >>= 1) m = fmaxf(m, __shfl_xor(m, off));
    __shared__ float wred[4], wsum[4];
    const int w = tid >> 6;
    if ((tid & 63) == 0) wred[w] = m;
    __syncthreads();
    const float M = fmaxf(fmaxf(wred[0], wred[1]), fmaxf(wred[2], wred[3]));
    float s = 0.f;
    #pragma unroll
    for (int i = 0; i < 8; ++i) { xv[i] = expf(xv[i] - M); s += xv[i]; }
    #pragma unroll
    for (int off = 32; off; off >>= 1) s += __shfl_xor(s, off);
    if ((tid & 63) == 0) wsum[w] = s;
    __syncthreads();
    const float inv = 1.f / (wsum[0] + wsum[1] + wsum[2] + wsum[3]);
    #pragma unroll
    for (int i = 0; i < 8; ++i) attn[b * S + tid + i * 256] = xv[i] * inv;
}

// ---------------- context: partial over S-chunks, then reduce ------------
__global__ __launch_bounds__(256) void ctx_partial(
    const float* __restrict__ enc, const float* __restrict__ attn,
    float* __restrict__ part, int rows)
{
    const int sc = blockIdx.x;
    const int b  = blockIdx.y;
    const int tid = threadIdx.x;
    const float* encb = enc + ((size_t)b * S + (size_t)sc * rows) * H;
    const float* wb = attn + b * S + sc * rows;
    __shared__ float wl[256];
    if (tid < rows) wl[tid] = wb[tid];
    __syncthreads();
    float4 acc = {0.f, 0.f, 0.f, 0.f};
    for (int s = 0; s < rows; ++s) {
        const float wgt = wl[s];
        const float4 e = *(const float4*)(encb + (size_t)s * H + tid * 4);
        acc.x += wgt * e.x; acc.y += wgt * e.y; acc.z += wgt * e.z; acc.w += wgt * e.w;
    }
    ((float4*)(part + ((size_t)(sc * B + b)) * H))[tid] = acc;
}

__global__ __launch_bounds__(256) void ctx_reduce(
    const float* __restrict__ part, float* __restrict__ ctx, int nch)
{
    const int i = blockIdx.x * 256 + threadIdx.x;
    float s = 0.f;
    for (int c = 0; c < nch; ++c) s += part[(size_t)c * (B * H) + i];
    ctx[i] = s;
}

extern "C" void kernel_launch(void* const* d_in, const int* in_sizes, int n_in,
                              void* d_out, int out_size, void* d_ws, size_t ws_size,
                              hipStream_t stream) {
    const float* hidden = (const float*)d_in[0];
    const float* enc    = (const float*)d_in[1];
    const float* W      = (const float*)d_in[2];
    const float* b_attn = (const float*)d_in[3];
    const float* v      = (const float*)d_in[4];
    float* ctx  = (float*)d_out;               // (B, H)
    float* attn = ctx + B * H;                 // (B, S)
    float* ws      = (float*)d_ws;
    float* region  = ws;                       // 524288 f32: score partials, then ctx part
    float* ph      = ws + 524288;              // 32768 f32
    _Float16* We_h = (_Float16*)(ws + 524288 + 32768);  // 1M halfs (primary only)

    proj_h_kernel<<<dim3(H / 4, B), 256, 0, stream>>>(hidden, W, b_attn, ph);

    const size_t need_primary = (size_t)(524288 + 32768 + 524288) * 4;
    if (ws_size >= need_primary) {
        conv_We<<<1024, 256, 0, stream>>>(W, We_h);
        score_v4<true><<<4096, 256, 0, stream>>>(enc, (const void*)We_h, ph, v, region);
    } else {
        score_v4<false><<<4096, 256, 0, stream>>>(enc, (const void*)W, ph, v, region);
    }
    softmax_kernel<<<dim3(B), 256, 0, stream>>>(region, attn);
    ctx_partial<<<dim3(16, B), 256, 0, stream>>>(enc, attn, region, 128);
    ctx_reduce<<<dim3((B * H) / 256), 256, 0, stream>>>(region, ctx, 16);
}

// Round 5
// 266.122 us; speedup vs baseline: 4.3446x; 1.1762x over previous
//
#include <hip/hip_runtime.h>
#include <hip/hip_bf16.h>

#define H 1024
#define B 32
#define S 2048

typedef __attribute__((ext_vector_type(8))) _Float16 h8;
typedef __attribute__((ext_vector_type(4))) _Float16 h4;
typedef __attribute__((ext_vector_type(4))) float f32x4;

__device__ __forceinline__ float fast_tanh(float x) {
    float a = __builtin_fabsf(x);
    float e = __expf(2.0f * a);
    float r = 1.0f - 2.0f / (e + 1.0f);   // == tanh(a)
    return __builtin_copysignf(r, x);
}

__device__ __forceinline__ void gload_lds16(const void* g, void* l) {
    __builtin_amdgcn_global_load_lds(
        (const __attribute__((address_space(1))) unsigned int*)g,
        (__attribute__((address_space(3))) unsigned int*)l, 16, 0, 0);
}

// ---------------- proj_h = h @ Wh^T + b_attn  (32 x 1024) ----------------
__global__ __launch_bounds__(256) void proj_h_kernel(
    const float* __restrict__ hidden, const float* __restrict__ W,
    const float* __restrict__ b_attn, float* __restrict__ ph)
{
    const int b = blockIdx.y;
    const int tid = threadIdx.x;
    __shared__ float hs[H];
    const float4* hr = (const float4*)(hidden + (size_t)(B + b) * H); // hidden[-1]
    ((float4*)hs)[tid] = hr[tid];
    __syncthreads();
    const int w = tid >> 6, lane = tid & 63;
    const int o = blockIdx.x * 4 + w;
    const float* wr = W + (size_t)o * (2 * H);
    float acc = 0.f;
    #pragma unroll
    for (int i = 0; i < 16; ++i) {
        const int k = i * 64 + lane;
        acc += wr[k] * hs[k];
    }
    #pragma unroll
    for (int off = 32; off; off >>= 1) acc += __shfl_xor(acc, off);
    if (lane == 0) ph[b * H + o] = acc + b_attn[o];
}

// ---------------- We (f32) -> We_h (fp16), row-major [1024][1024] --------
__global__ __launch_bounds__(256) void conv_We(
    const float* __restrict__ W, _Float16* __restrict__ We_h)
{
    const int o = blockIdx.x;
    const int t = threadIdx.x;
    float4 f = *(const float4*)(W + (size_t)o * 2048 + 1024 + t * 4);
    h4 hv = {(_Float16)f.x, (_Float16)f.y, (_Float16)f.z, (_Float16)f.w};
    *(h4*)(We_h + (size_t)o * 1024 + t * 4) = hv;
}

// ------- score GEMM v5: pure-DMA staging (A f32, B fp16), m97 2-barrier --
// Grid 512(M) x 8(N), XCD-swizzled. partial[nb][m] = sum_{128 cols} v*tanh(C+ph).
// A: global_load_lds f32 tile 128x64 (32 KB), slot-swizzle ^(r&15) over 16 slots.
// B: global_load_lds fp16 tile 128x64 (16 KB), slot-swizzle ^(n&7) over 8 slots.
__global__ __launch_bounds__(256, 3) void score_v5(
    const float* __restrict__ enc, const _Float16* __restrict__ We_h,
    const float* __restrict__ ph, const float* __restrict__ v,
    float* __restrict__ partial)
{
    __shared__ float    As[128 * 64];   // 32 KB
    __shared__ _Float16 Bs[128 * 64];   // 16 KB
    __shared__ float slds[256];

    const int tid = threadIdx.x;
    const int bid = blockIdx.x;
    // XCD swizzle: the 8 nb-blocks of one M-panel share an XCD's L2
    const int x  = bid & 7;
    const int ii = bid >> 3;
    const int nb = ii & 7;
    const int mt = (ii >> 3) * 8 + x;      // 0..511
    const int b  = mt >> 4;

    const int lane = tid & 63;
    const int wid  = tid >> 6;
    const int wm = wid >> 1, wn = wid & 1;
    const int l15 = lane & 15, lg = lane >> 4;

    // DMA lane maps
    const int a_rsub = lane >> 4;          // row within 4-row chunk
    const int a_sl   = lane & 15;          // LDS 16B slot within row (of 16)
    const int b_rsub = lane >> 3;          // row within 8-row group
    const int b_sl   = lane & 7;           // LDS 16B slot within row (of 8)

    f32x4 acc[4][4];
    #pragma unroll
    for (int mi = 0; mi < 4; ++mi)
        #pragma unroll
        for (int ni = 0; ni < 4; ++ni) acc[mi][ni] = (f32x4){0.f, 0.f, 0.f, 0.f};

    for (int kt = 0; kt < 16; ++kt) {
        const int k0 = kt * 64;
        __syncthreads();                    // prev compute done -> LDS reusable
        // A tile: 8 issues/wave, 4 rows per chunk of 64 lanes
        #pragma unroll
        for (int i = 0; i < 8; ++i) {
            const int c = i * 4 + wid;      // chunk 0..31
            const int r = c * 4 + a_rsub;   // row 0..127
            gload_lds16(enc + (size_t)(mt * 128 + r) * H + k0 + ((a_sl ^ (r & 15)) * 4),
                        (char*)As + c * 1024);
        }
        // B tile: 4 issues/wave, 8 rows per group
        #pragma unroll
        for (int q = 0; q < 4; ++q) {
            const int n  = q * 32 + wid * 8 + b_rsub;
            const int gn = nb * 128 + n;
            gload_lds16(We_h + (size_t)gn * H + k0 + ((b_sl ^ (n & 7)) * 8),
                        (char*)Bs + (q * 32 + wid * 8) * 128);
        }
        __syncthreads();                    // compiler drains vmcnt(0) here
        #pragma unroll
        for (int ks = 0; ks < 2; ++ks) {
            h8 ah[4], bh[4];
            #pragma unroll
            for (int mi = 0; mi < 4; ++mi) {
                const int r  = wm * 64 + mi * 16 + l15;
                const int s0 = ks * 8 + lg * 2;     // two 16B f32 slots = 8 floats
                f32x4 f0 = *(const f32x4*)((const char*)As + r * 256 + ((s0 ^ (r & 15)) * 16));
                f32x4 f1 = *(const f32x4*)((const char*)As + r * 256 + (((s0 + 1) ^ (r & 15)) * 16));
                ah[mi] = (h8){(_Float16)f0[0], (_Float16)f0[1], (_Float16)f0[2], (_Float16)f0[3],
                              (_Float16)f1[0], (_Float16)f1[1], (_Float16)f1[2], (_Float16)f1[3]};
            }
            #pragma unroll
            for (int ni = 0; ni < 4; ++ni) {
                const int r  = wn * 64 + ni * 16 + l15;
                const int sl = ks * 4 + lg;
                bh[ni] = *(const h8*)((const char*)Bs + r * 128 + ((sl ^ (r & 7)) * 16));
            }
            #pragma unroll
            for (int mi = 0; mi < 4; ++mi)
                #pragma unroll
                for (int ni = 0; ni < 4; ++ni)
                    acc[mi][ni] = __builtin_amdgcn_mfma_f32_16x16x32_f16(
                        ah[mi], bh[ni], acc[mi][ni], 0, 0, 0);
        }
    }

    // epilogue: tanh + v-dot over this block's 128 cols -> per-row partial
    float vreg[4], preg[4];
    #pragma unroll
    for (int ni = 0; ni < 4; ++ni) {
        const int gcol = nb * 128 + wn * 64 + ni * 16 + l15;
        vreg[ni] = v[gcol];
        preg[ni] = ph[b * H + gcol];
    }
    #pragma unroll
    for (int mi = 0; mi < 4; ++mi) {
        #pragma unroll
        for (int j = 0; j < 4; ++j) {
            float p = 0.f;
            #pragma unroll
            for (int ni = 0; ni < 4; ++ni)
                p += vreg[ni] * fast_tanh(acc[mi][ni][j] + preg[ni]);
            p += __shfl_xor(p, 1); p += __shfl_xor(p, 2);
            p += __shfl_xor(p, 4); p += __shfl_xor(p, 8);
            if (l15 == 0)
                slds[wn * 128 + wm * 64 + mi * 16 + lg * 4 + j] = p;
        }
    }
    __syncthreads();
    if (tid < 128)
        partial[(size_t)nb * (B * S) + mt * 128 + tid] = slds[tid] + slds[128 + tid];
}

// ---- fallback score (R4 path, B reg-staged from f32 W; only if ws tiny) ----
__global__ __launch_bounds__(256) void score_v4f(
    const float* __restrict__ enc, const float* __restrict__ Wf,
    const float* __restrict__ ph, const float* __restrict__ v,
    float* __restrict__ partial)
{
    __shared__ _Float16 As[128 * 64];
    __shared__ _Float16 Bs[128 * 64];
    __shared__ float slds[256];
    const int tid = threadIdx.x;
    const int bid = blockIdx.x;
    const int x  = bid & 7;
    const int ii = bid >> 3;
    const int nb = ii & 7;
    const int mt = (ii >> 3) * 8 + x;
    const int b  = mt >> 4;
    const int lane = tid & 63;
    const int wid  = tid >> 6;
    const int wm = wid >> 1, wn = wid & 1;
    const int l15 = lane & 15, lg = lane >> 4;
    const int arow  = tid >> 3;
    const int aslot = tid & 7;
    f32x4 acc[4][4];
    #pragma unroll
    for (int mi = 0; mi < 4; ++mi)
        #pragma unroll
        for (int ni = 0; ni < 4; ++ni) acc[mi][ni] = (f32x4){0.f, 0.f, 0.f, 0.f};
    for (int kt = 0; kt < 16; ++kt) {
        const int k0 = kt * 64;
        __syncthreads();
        #pragma unroll
        for (int p = 0; p < 4; ++p) {
            const int m = p * 32 + arow;
            const float* src = enc + (size_t)(mt * 128 + m) * H + k0 + aslot * 8;
            float4 f0 = *(const float4*)src;
            float4 f1 = *(const float4*)(src + 4);
            h8 hv = {(_Float16)f0.x, (_Float16)f0.y, (_Float16)f0.z, (_Float16)f0.w,
                     (_Float16)f1.x, (_Float16)f1.y, (_Float16)f1.z, (_Float16)f1.w};
            *(h8*)((char*)As + m * 128 + ((aslot ^ (m & 7)) * 16)) = hv;
        }
        #pragma unroll
        for (int p = 0; p < 4; ++p) {
            const int n  = p * 32 + arow;
            const int gn = nb * 128 + n;
            const float* src = Wf + (size_t)gn * 2048 + 1024 + k0 + aslot * 8;
            float4 f0 = *(const float4*)src;
            float4 f1 = *(const float4*)(src + 4);
            h8 hv = {(_Float16)f0.x, (_Float16)f0.y, (_Float16)f0.z, (_Float16)f0.w,
                     (_Float16)f1.x, (_Float16)f1.y, (_Float16)f1.z, (_Float16)f1.w};
            *(h8*)((char*)Bs + n * 128 + ((aslot ^ (n & 7)) * 16)) = hv;
        }
        __syncthreads();
        #pragma unroll
        for (int ks = 0; ks < 2; ++ks) {
            h8 ah[4], bh[4];
            const int sl = ks * 4 + lg;
            #pragma unroll
            for (int mi = 0; mi < 4; ++mi) {
                const int r = wm * 64 + mi * 16 + l15;
                ah[mi] = *(const h8*)((char*)As + r * 128 + 16 * (sl ^ (r & 7)));
            }
            #pragma unroll
            for (int ni = 0; ni < 4; ++ni) {
                const int r = wn * 64 + ni * 16 + l15;
                bh[ni] = *(const h8*)((char*)Bs + r * 128 + 16 * (sl ^ (r & 7)));
            }
            #pragma unroll
            for (int mi = 0; mi < 4; ++mi)
                #pragma unroll
                for (int ni = 0; ni < 4; ++ni)
                    acc[mi][ni] = __builtin_amdgcn_mfma_f32_16x16x32_f16(
                        ah[mi], bh[ni], acc[mi][ni], 0, 0, 0);
        }
    }
    float vreg[4], preg[4];
    #pragma unroll
    for (int ni = 0; ni < 4; ++ni) {
        const int gcol = nb * 128 + wn * 64 + ni * 16 + l15;
        vreg[ni] = v[gcol];
        preg[ni] = ph[b * H + gcol];
    }
    #pragma unroll
    for (int mi = 0; mi < 4; ++mi) {
        #pragma unroll
        for (int j = 0; j < 4; ++j) {
            float p = 0.f;
            #pragma unroll
            for (int ni = 0; ni < 4; ++ni)
                p += vreg[ni] * fast_tanh(acc[mi][ni][j] + preg[ni]);
            p += __shfl_xor(p, 1); p += __shfl_xor(p, 2);
            p += __shfl_xor(p, 4); p += __shfl_xor(p, 8);
            if (l15 == 0)
                slds[wn * 128 + wm * 64 + mi * 16 + lg * 4 + j] = p;
        }
    }
    __syncthreads();
    if (tid < 128)
        partial[(size_t)nb * (B * S) + mt * 128 + tid] = slds[tid] + slds[128 + tid];
}

// ---------------- softmax over S per batch (sums the 8 N-partials) -------
__global__ __launch_bounds__(256) void softmax_kernel(
    const float* __restrict__ partial, float* __restrict__ attn)
{
    const int b = blockIdx.x, tid = threadIdx.x;
    float xv[8];
    float m = -1e30f;
    #pragma unroll
    for (int i = 0; i < 8; ++i) {
        float s = 0.f;
        #pragma unroll
        for (int nb = 0; nb < 8; ++nb)
            s += partial[(size_t)nb * (B * S) + b * S + tid + i * 256];
        xv[i] = s;
        m = fmaxf(m, s);
    }
    #pragma unroll
    for (int off = 32; off; off >>= 1) m = fmaxf(m, __shfl_xor(m, off));
    __shared__ float wred[4], wsum[4];
    const int w = tid >> 6;
    if ((tid & 63) == 0) wred[w] = m;
    __syncthreads();
    const float M = fmaxf(fmaxf(wred[0], wred[1]), fmaxf(wred[2], wred[3]));
    float s = 0.f;
    #pragma unroll
    for (int i = 0; i < 8; ++i) { xv[i] = expf(xv[i] - M); s += xv[i]; }
    #pragma unroll
    for (int off = 32; off; off >>= 1) s += __shfl_xor(s, off);
    if ((tid & 63) == 0) wsum[w] = s;
    __syncthreads();
    const float inv = 1.f / (wsum[0] + wsum[1] + wsum[2] + wsum[3]);
    #pragma unroll
    for (int i = 0; i < 8; ++i) attn[b * S + tid + i * 256] = xv[i] * inv;
}

// ---------------- context: partial over S-chunks, then reduce ------------
__global__ __launch_bounds__(256) void ctx_partial(
    const float* __restrict__ enc, const float* __restrict__ attn,
    float* __restrict__ part, int rows)
{
    const int sc = blockIdx.x;
    const int b  = blockIdx.y;
    const int tid = threadIdx.x;
    const float* encb = enc + ((size_t)b * S + (size_t)sc * rows) * H;
    const float* wb = attn + b * S + sc * rows;
    __shared__ float wl[256];
    if (tid < rows) wl[tid] = wb[tid];
    __syncthreads();
    float4 acc = {0.f, 0.f, 0.f, 0.f};
    for (int s = 0; s < rows; ++s) {
        const float wgt = wl[s];
        const float4 e = *(const float4*)(encb + (size_t)s * H + tid * 4);
        acc.x += wgt * e.x; acc.y += wgt * e.y; acc.z += wgt * e.z; acc.w += wgt * e.w;
    }
    ((float4*)(part + ((size_t)(sc * B + b)) * H))[tid] = acc;
}

__global__ __launch_bounds__(256) void ctx_reduce(
    const float* __restrict__ part, float* __restrict__ ctx, int nch)
{
    const int i = blockIdx.x * 256 + threadIdx.x;
    float s = 0.f;
    for (int c = 0; c < nch; ++c) s += part[(size_t)c * (B * H) + i];
    ctx[i] = s;
}

extern "C" void kernel_launch(void* const* d_in, const int* in_sizes, int n_in,
                              void* d_out, int out_size, void* d_ws, size_t ws_size,
                              hipStream_t stream) {
    const float* hidden = (const float*)d_in[0];
    const float* enc    = (const float*)d_in[1];
    const float* W      = (const float*)d_in[2];
    const float* b_attn = (const float*)d_in[3];
    const float* v      = (const float*)d_in[4];
    float* ctx  = (float*)d_out;               // (B, H)
    float* attn = ctx + B * H;                 // (B, S)
    float* ws      = (float*)d_ws;
    float* region  = ws;                       // 524288 f32: score partials, then ctx part
    float* ph      = ws + 524288;              // 32768 f32
    _Float16* We_h = (_Float16*)(ws + 524288 + 32768);  // 1M halfs

    proj_h_kernel<<<dim3(H / 4, B), 256, 0, stream>>>(hidden, W, b_attn, ph);

    const size_t need_primary = (size_t)(524288 + 32768 + 524288) * 4;
    if (ws_size >= need_primary) {
        conv_We<<<1024, 256, 0, stream>>>(W, We_h);
        score_v5<<<4096, 256, 0, stream>>>(enc, We_h, ph, v, region);
    } else {
        score_v4f<<<4096, 256, 0, stream>>>(enc, W, ph, v, region);
    }
    softmax_kernel<<<dim3(B), 256, 0, stream>>>(region, attn);
    ctx_partial<<<dim3(16, B), 256, 0, stream>>>(enc, attn, region, 128);
    ctx_reduce<<<dim3((B * H) / 256), 256, 0, stream>>>(region, ctx, 16);
}